// Round 5
// baseline (65.546 us; speedup 1.0000x reference)
//
#include <hip/hip_runtime.h>

#define C_DIM 1000
#define CPAD  1024          // padded per-slice column stride (words)

// ---------------------------------------------------------------------------
// Kernel 1: streaming partial reduction, no global atomics (store mode).
// 1024 threads = 4 row-groups x 256 (250 active). Group g of block b streams
// rows v = b*4+g, v+4*grid, ... Each active thread owns 4 columns.
// Groups merge via LDS; block stores its 3000-word partial to slice blockIdx.
// Fallback (store_mode=0): atomicAdd into slice blockIdx % S.
//
// softplus(x)  = max(x,0)  + ln2 * log2(1 + 2^(-|x|*log2e))   (log2 term shared)
// Labels are {0,1}; counts pack as (n_pos | n_neg<<16).
//
// sched_barrier(0) after the load cluster: forbids the scheduler from sinking
// loads into the compute (R4: VGPR=36 => loads serialized, 1 in flight, HBM
// 16%). With the barrier, all 8 loads issue first (8 KB/wave in flight) and
// loads(i+1) overlap compute(i).
// ---------------------------------------------------------------------------
__global__ __launch_bounds__(1024) void nrl_partial_kernel(
    const float* __restrict__ pred,
    const int*   __restrict__ labels,
    float*        __restrict__ ws_sp_pos,   // [S][CPAD]
    float*        __restrict__ ws_sp_neg,   // [S][CPAD]
    unsigned int* __restrict__ ws_cnt,      // [S][CPAD]
    int N, int S, int store_mode)
{
    const int g   = threadIdx.x >> 8;     // row-group 0..3
    const int tid = threadIdx.x & 255;    // lane-in-group

    __shared__ float        s_sp[4][CPAD];
    __shared__ float        s_sn[4][CPAD];
    __shared__ unsigned int s_ct[4][CPAD];

    const float NEG_LOG2E = -1.4426950408889634f;
    const float LN2       =  0.6931471805599453f;

    float l2p[4] = {0.f,0.f,0.f,0.f};
    float l2n[4] = {0.f,0.f,0.f,0.f};
    float lip[4] = {0.f,0.f,0.f,0.f};
    float lin[4] = {0.f,0.f,0.f,0.f};
    unsigned int cnt[4] = {0u,0u,0u,0u};

#define PROC(P, Y)                                                          \
    {                                                                       \
        const float px[4] = {(P).x, (P).y, (P).z, (P).w};                   \
        const int   yy[4] = {(Y).x, (Y).y, (Y).z, (Y).w};                   \
        _Pragma("unroll")                                                   \
        for (int j = 0; j < 4; ++j) {                                       \
            const float x  = px[j];                                         \
            const float u  = NEG_LOG2E * fabsf(x);                          \
            const float e2 = __builtin_amdgcn_exp2f(u);                     \
            const float l2 = __builtin_amdgcn_logf(1.0f + e2);              \
            const float r  = fmaxf(x, 0.0f);                                \
            const float rn = r - x; /* = max(-x,0) */                       \
            const bool isp = (yy[j] == 1);                                  \
            l2p[j] += isp ? l2 : 0.0f;                                      \
            l2n[j] += isp ? 0.0f : l2;                                      \
            lip[j] += isp ? rn : 0.0f;                                      \
            lin[j] += isp ? 0.0f : r;                                       \
            cnt[j] += isp ? 1u : 0x10000u;                                  \
        }                                                                   \
    }

    if (tid < 250) {
        const int c0 = tid * 4;
        const int v       = (blockIdx.x << 2) | g;
        const int vstride = gridDim.x << 2;

        int r = v;
        for (; r + 3 * vstride < N; r += 4 * vstride) {
            const size_t b0 = (size_t)r * C_DIM + c0;
            const size_t b1 = (size_t)(r +     vstride) * C_DIM + c0;
            const size_t b2 = (size_t)(r + 2 * vstride) * C_DIM + c0;
            const size_t b3 = (size_t)(r + 3 * vstride) * C_DIM + c0;
            const float4 p0 = *reinterpret_cast<const float4*>(pred + b0);
            const int4   y0 = *reinterpret_cast<const int4*>(labels + b0);
            const float4 p1 = *reinterpret_cast<const float4*>(pred + b1);
            const int4   y1 = *reinterpret_cast<const int4*>(labels + b1);
            const float4 p2 = *reinterpret_cast<const float4*>(pred + b2);
            const int4   y2 = *reinterpret_cast<const int4*>(labels + b2);
            const float4 p3 = *reinterpret_cast<const float4*>(pred + b3);
            const int4   y3 = *reinterpret_cast<const int4*>(labels + b3);
            __builtin_amdgcn_sched_barrier(0);   // keep all 8 loads issued first
            PROC(p0, y0) PROC(p1, y1) PROC(p2, y2) PROC(p3, y3)
        }
        for (; r < N; r += vstride) {
            const size_t b0 = (size_t)r * C_DIM + c0;
            const float4 p0 = *reinterpret_cast<const float4*>(pred + b0);
            const int4   y0 = *reinterpret_cast<const int4*>(labels + b0);
            PROC(p0, y0)
        }
#undef PROC

        float4 vp, vn; uint4 vc;
        vp.x = l2p[0]*LN2 + lip[0]; vp.y = l2p[1]*LN2 + lip[1];
        vp.z = l2p[2]*LN2 + lip[2]; vp.w = l2p[3]*LN2 + lip[3];
        vn.x = l2n[0]*LN2 + lin[0]; vn.y = l2n[1]*LN2 + lin[1];
        vn.z = l2n[2]*LN2 + lin[2]; vn.w = l2n[3]*LN2 + lin[3];
        vc.x = cnt[0]; vc.y = cnt[1]; vc.z = cnt[2]; vc.w = cnt[3];
        *reinterpret_cast<float4*>(&s_sp[g][c0]) = vp;
        *reinterpret_cast<float4*>(&s_sn[g][c0]) = vn;
        *reinterpret_cast<uint4*>(&s_ct[g][c0])  = vc;
    }
    __syncthreads();

    const int t = threadIdx.x;
    if (t < C_DIM) {
        const float sp = s_sp[0][t] + s_sp[1][t] + s_sp[2][t] + s_sp[3][t];
        const float sn = s_sn[0][t] + s_sn[1][t] + s_sn[2][t] + s_sn[3][t];
        const unsigned int c = s_ct[0][t] + s_ct[1][t] + s_ct[2][t] + s_ct[3][t];
        if (store_mode) {
            const size_t off = (size_t)blockIdx.x * CPAD + t;
            ws_sp_pos[off] = sp;
            ws_sp_neg[off] = sn;
            ws_cnt[off]    = c;
        } else {
            const size_t off = (size_t)(blockIdx.x % S) * CPAD + t;
            atomicAdd(&ws_sp_pos[off], sp);
            atomicAdd(&ws_sp_neg[off], sn);
            atomicAdd(&ws_cnt[off],    c);
        }
    }
}

// ---------------------------------------------------------------------------
// Kernel 2: block j reduces columns 4j..4j+3 across S slices (loop stride 256),
// computes per-class loss + validity, atomically accumulates LV[0]/LV[1].
// ---------------------------------------------------------------------------
__global__ __launch_bounds__(256) void nrl_reduce_kernel(
    const float*        __restrict__ ws_sp_pos,
    const float*        __restrict__ ws_sp_neg,
    const unsigned int* __restrict__ ws_cnt,
    float* __restrict__ LV, int S)
{
    const int j  = blockIdx.x;        // column quad
    const int c0 = j * 4;

    float4 a = {0.f,0.f,0.f,0.f};
    float4 b = {0.f,0.f,0.f,0.f};
    uint4  c = {0u,0u,0u,0u};
    for (int s = threadIdx.x; s < S; s += 256) {
        const size_t off = (size_t)s * CPAD + c0;
        const float4 aa = *reinterpret_cast<const float4*>(ws_sp_pos + off);
        const float4 bb = *reinterpret_cast<const float4*>(ws_sp_neg + off);
        const uint4  cc = *reinterpret_cast<const uint4*>(ws_cnt + off);
        a.x += aa.x; a.y += aa.y; a.z += aa.z; a.w += aa.w;
        b.x += bb.x; b.y += bb.y; b.z += bb.z; b.w += bb.w;
        c.x += cc.x; c.y += cc.y; c.z += cc.z; c.w += cc.w;
    }

#pragma unroll
    for (int off = 32; off > 0; off >>= 1) {
        a.x += __shfl_down(a.x, off); a.y += __shfl_down(a.y, off);
        a.z += __shfl_down(a.z, off); a.w += __shfl_down(a.w, off);
        b.x += __shfl_down(b.x, off); b.y += __shfl_down(b.y, off);
        b.z += __shfl_down(b.z, off); b.w += __shfl_down(b.w, off);
        c.x += __shfl_down(c.x, off); c.y += __shfl_down(c.y, off);
        c.z += __shfl_down(c.z, off); c.w += __shfl_down(c.w, off);
    }

    __shared__ float4 w_a[4];
    __shared__ float4 w_b[4];
    __shared__ uint4  w_c[4];
    const int wid  = threadIdx.x >> 6;
    const int lane = threadIdx.x & 63;
    if (lane == 0) { w_a[wid] = a; w_b[wid] = b; w_c[wid] = c; }
    __syncthreads();

    if (threadIdx.x == 0) {
        float sp[4] = {0.f,0.f,0.f,0.f};
        float sn[4] = {0.f,0.f,0.f,0.f};
        unsigned int ct[4] = {0u,0u,0u,0u};
#pragma unroll
        for (int w = 0; w < 4; ++w) {
            sp[0] += w_a[w].x; sp[1] += w_a[w].y; sp[2] += w_a[w].z; sp[3] += w_a[w].w;
            sn[0] += w_b[w].x; sn[1] += w_b[w].y; sn[2] += w_b[w].z; sn[3] += w_b[w].w;
            ct[0] += w_c[w].x; ct[1] += w_c[w].y; ct[2] += w_c[w].z; ct[3] += w_c[w].w;
        }
        float L = 0.f, V = 0.f;
#pragma unroll
        for (int q = 0; q < 4; ++q) {
            const float np = (float)(ct[q] & 0xFFFFu);
            const float nn = (float)(ct[q] >> 16);
            const bool valid = (np > 0.f) && (nn > 0.f);
            const float l = sp[q] / fmaxf(np, 1.f) + sn[q] / fmaxf(nn, 1.f);
            L += valid ? l   : 0.f;
            V += valid ? 1.f : 0.f;
        }
        atomicAdd(&LV[0], L);
        atomicAdd(&LV[1], V);
    }
}

// ---------------------------------------------------------------------------
__global__ void nrl_final_kernel(const float* __restrict__ LV,
                                 float* __restrict__ out)
{
    out[0] = LV[0] / fmaxf(LV[1], 1.0f);
}

// ---------------------------------------------------------------------------
extern "C" void kernel_launch(void* const* d_in, const int* in_sizes, int n_in,
                              void* d_out, int out_size, void* d_ws, size_t ws_size,
                              hipStream_t stream)
{
    const float* pred   = (const float*)d_in[0];
    const int*   labels = (const int*)d_in[1];
    const int N = in_sizes[0] / C_DIM;

    const size_t bytes512 = 3ull * 512 * CPAD * 4ull + 16;   // 6.30 MB
    const size_t bytes256 = 3ull * 256 * CPAD * 4ull + 16;   // 3.15 MB

    int store_mode, S, nblk;
    if (ws_size >= bytes512) {
        store_mode = 1; S = 512; nblk = 512;   // 2 blocks/CU -> 32 waves/CU
    } else if (ws_size >= bytes256) {
        store_mode = 1; S = 256; nblk = 256;   // R4 regime (proven to fit)
    } else {
        store_mode = 0; nblk = 256;
        S = (int)((ws_size - 16) / (3ull * CPAD * 4ull));
        if (S > 64) S = 64;
        if (S < 1)  S = 1;
    }

    float*        ws_sp_pos = (float*)d_ws;
    float*        ws_sp_neg = ws_sp_pos + (size_t)S * CPAD;
    unsigned int* ws_cnt    = (unsigned int*)(ws_sp_neg + (size_t)S * CPAD);
    float*        LV        = (float*)(ws_cnt + (size_t)S * CPAD);

    if (store_mode) {
        hipMemsetAsync(LV, 0, 2 * sizeof(float), stream);
    } else {
        hipMemsetAsync(d_ws, 0, 3ull * S * CPAD * 4ull + 2 * sizeof(float), stream);
    }

    nrl_partial_kernel<<<nblk, 1024, 0, stream>>>(pred, labels,
                                                  ws_sp_pos, ws_sp_neg, ws_cnt,
                                                  N, S, store_mode);
    nrl_reduce_kernel<<<250, 256, 0, stream>>>(ws_sp_pos, ws_sp_neg,
                                               ws_cnt, LV, S);
    nrl_final_kernel<<<1, 1, 0, stream>>>(LV, (float*)d_out);
}

// Round 6
// 65.529 us; speedup vs baseline: 1.0003x; 1.0003x over previous
//
#include <hip/hip_runtime.h>

#define C_DIM 1000
#define CPAD  1024          // padded per-slice column stride (words)

typedef float f32x4 __attribute__((ext_vector_type(4)));
typedef int   i32x4 __attribute__((ext_vector_type(4)));

// Inline-asm 16B loads: the "=v" result ties the load to its consumers, so the
// compiler CANNOT serialize load->wait->use (R4/R5: VGPR=36 proved it did with
// plain loads). All 8 loads issue back-to-back; one vmcnt(0) drains them.
#define GLOAD(dst, addr) \
    asm volatile("global_load_dwordx4 %0, %1, off" : "=v"(dst) : "v"(addr))

// ---------------------------------------------------------------------------
// Kernel 1: streaming partial reduction, no global atomics (store mode).
// 1024 threads = 4 row-groups x 256 (250 active). Group g of block b streams
// rows v = b*4+g, v+4*grid, ... Each active thread owns 4 columns.
// Groups merge via LDS; block stores its 3000-word partial to slice blockIdx.
//
// softplus(x)  = max(x,0)  + ln2 * log2(1 + 2^(-|x|*log2e))   (log2 term shared)
// Labels are {0,1}; counts pack as (n_pos | n_neg<<16).
// ---------------------------------------------------------------------------
__global__ __launch_bounds__(1024) void nrl_partial_kernel(
    const float* __restrict__ pred,
    const int*   __restrict__ labels,
    float*        __restrict__ ws_sp_pos,   // [S][CPAD]
    float*        __restrict__ ws_sp_neg,   // [S][CPAD]
    unsigned int* __restrict__ ws_cnt,      // [S][CPAD]
    int N, int S, int store_mode)
{
    const int g   = threadIdx.x >> 8;     // row-group 0..3
    const int tid = threadIdx.x & 255;    // lane-in-group

    __shared__ float        s_sp[4][CPAD];
    __shared__ float        s_sn[4][CPAD];
    __shared__ unsigned int s_ct[4][CPAD];

    const float NEG_LOG2E = -1.4426950408889634f;
    const float LN2       =  0.6931471805599453f;

    float l2p[4] = {0.f,0.f,0.f,0.f};
    float l2n[4] = {0.f,0.f,0.f,0.f};
    float lip[4] = {0.f,0.f,0.f,0.f};
    float lin[4] = {0.f,0.f,0.f,0.f};
    unsigned int cnt[4] = {0u,0u,0u,0u};

#define PROC(P, Y)                                                          \
    {                                                                       \
        _Pragma("unroll")                                                   \
        for (int j = 0; j < 4; ++j) {                                       \
            const float x  = (P)[j];                                        \
            const float u  = NEG_LOG2E * fabsf(x);                          \
            const float e2 = __builtin_amdgcn_exp2f(u);                     \
            const float l2 = __builtin_amdgcn_logf(1.0f + e2);              \
            const float r  = fmaxf(x, 0.0f);                                \
            const float rn = r - x; /* = max(-x,0) */                       \
            const bool isp = ((Y)[j] == 1);                                 \
            l2p[j] += isp ? l2 : 0.0f;                                      \
            l2n[j] += isp ? 0.0f : l2;                                      \
            lip[j] += isp ? rn : 0.0f;                                      \
            lin[j] += isp ? 0.0f : r;                                       \
            cnt[j] += isp ? 1u : 0x10000u;                                  \
        }                                                                   \
    }

    if (tid < 250) {
        const int c0 = tid * 4;
        const int v       = (blockIdx.x << 2) | g;
        const int vstride = gridDim.x << 2;

        int r = v;
        for (; r + 3 * vstride < N; r += 4 * vstride) {
            const size_t b0 = (size_t)r * C_DIM + c0;
            const size_t b1 = (size_t)(r +     vstride) * C_DIM + c0;
            const size_t b2 = (size_t)(r + 2 * vstride) * C_DIM + c0;
            const size_t b3 = (size_t)(r + 3 * vstride) * C_DIM + c0;

            f32x4 p0, p1, p2, p3;
            i32x4 y0, y1, y2, y3;
            GLOAD(p0, pred + b0);   GLOAD(y0, labels + b0);
            GLOAD(p1, pred + b1);   GLOAD(y1, labels + b1);
            GLOAD(p2, pred + b2);   GLOAD(y2, labels + b2);
            GLOAD(p3, pred + b3);   GLOAD(y3, labels + b3);
            asm volatile("s_waitcnt vmcnt(0)" ::: "memory");
            __builtin_amdgcn_sched_barrier(0);   // rule #18: keep VALU below the wait
            PROC(p0, y0) PROC(p1, y1) PROC(p2, y2) PROC(p3, y3)
        }
        for (; r < N; r += vstride) {
            const size_t b0 = (size_t)r * C_DIM + c0;
            const f32x4 p0 = *reinterpret_cast<const f32x4*>(pred + b0);
            const i32x4 y0 = *reinterpret_cast<const i32x4*>(labels + b0);
            PROC(p0, y0)
        }
#undef PROC

        float4 vp, vn; uint4 vc;
        vp.x = l2p[0]*LN2 + lip[0]; vp.y = l2p[1]*LN2 + lip[1];
        vp.z = l2p[2]*LN2 + lip[2]; vp.w = l2p[3]*LN2 + lip[3];
        vn.x = l2n[0]*LN2 + lin[0]; vn.y = l2n[1]*LN2 + lin[1];
        vn.z = l2n[2]*LN2 + lin[2]; vn.w = l2n[3]*LN2 + lin[3];
        vc.x = cnt[0]; vc.y = cnt[1]; vc.z = cnt[2]; vc.w = cnt[3];
        *reinterpret_cast<float4*>(&s_sp[g][c0]) = vp;
        *reinterpret_cast<float4*>(&s_sn[g][c0]) = vn;
        *reinterpret_cast<uint4*>(&s_ct[g][c0])  = vc;
    }
    __syncthreads();

    const int t = threadIdx.x;
    if (t < C_DIM) {
        const float sp = s_sp[0][t] + s_sp[1][t] + s_sp[2][t] + s_sp[3][t];
        const float sn = s_sn[0][t] + s_sn[1][t] + s_sn[2][t] + s_sn[3][t];
        const unsigned int c = s_ct[0][t] + s_ct[1][t] + s_ct[2][t] + s_ct[3][t];
        if (store_mode) {
            const size_t off = (size_t)blockIdx.x * CPAD + t;
            ws_sp_pos[off] = sp;
            ws_sp_neg[off] = sn;
            ws_cnt[off]    = c;
        } else {
            const size_t off = (size_t)(blockIdx.x % S) * CPAD + t;
            atomicAdd(&ws_sp_pos[off], sp);
            atomicAdd(&ws_sp_neg[off], sn);
            atomicAdd(&ws_cnt[off],    c);
        }
    }
}

// ---------------------------------------------------------------------------
// Kernel 2: block j reduces columns 4j..4j+3 across S slices (loop stride 256),
// computes per-class loss + validity, atomically accumulates LV[0]/LV[1].
// ---------------------------------------------------------------------------
__global__ __launch_bounds__(256) void nrl_reduce_kernel(
    const float*        __restrict__ ws_sp_pos,
    const float*        __restrict__ ws_sp_neg,
    const unsigned int* __restrict__ ws_cnt,
    float* __restrict__ LV, int S)
{
    const int j  = blockIdx.x;        // column quad
    const int c0 = j * 4;

    float4 a = {0.f,0.f,0.f,0.f};
    float4 b = {0.f,0.f,0.f,0.f};
    uint4  c = {0u,0u,0u,0u};
    for (int s = threadIdx.x; s < S; s += 256) {
        const size_t off = (size_t)s * CPAD + c0;
        const float4 aa = *reinterpret_cast<const float4*>(ws_sp_pos + off);
        const float4 bb = *reinterpret_cast<const float4*>(ws_sp_neg + off);
        const uint4  cc = *reinterpret_cast<const uint4*>(ws_cnt + off);
        a.x += aa.x; a.y += aa.y; a.z += aa.z; a.w += aa.w;
        b.x += bb.x; b.y += bb.y; b.z += bb.z; b.w += bb.w;
        c.x += cc.x; c.y += cc.y; c.z += cc.z; c.w += cc.w;
    }

#pragma unroll
    for (int off = 32; off > 0; off >>= 1) {
        a.x += __shfl_down(a.x, off); a.y += __shfl_down(a.y, off);
        a.z += __shfl_down(a.z, off); a.w += __shfl_down(a.w, off);
        b.x += __shfl_down(b.x, off); b.y += __shfl_down(b.y, off);
        b.z += __shfl_down(b.z, off); b.w += __shfl_down(b.w, off);
        c.x += __shfl_down(c.x, off); c.y += __shfl_down(c.y, off);
        c.z += __shfl_down(c.z, off); c.w += __shfl_down(c.w, off);
    }

    __shared__ float4 w_a[4];
    __shared__ float4 w_b[4];
    __shared__ uint4  w_c[4];
    const int wid  = threadIdx.x >> 6;
    const int lane = threadIdx.x & 63;
    if (lane == 0) { w_a[wid] = a; w_b[wid] = b; w_c[wid] = c; }
    __syncthreads();

    if (threadIdx.x == 0) {
        float sp[4] = {0.f,0.f,0.f,0.f};
        float sn[4] = {0.f,0.f,0.f,0.f};
        unsigned int ct[4] = {0u,0u,0u,0u};
#pragma unroll
        for (int w = 0; w < 4; ++w) {
            sp[0] += w_a[w].x; sp[1] += w_a[w].y; sp[2] += w_a[w].z; sp[3] += w_a[w].w;
            sn[0] += w_b[w].x; sn[1] += w_b[w].y; sn[2] += w_b[w].z; sn[3] += w_b[w].w;
            ct[0] += w_c[w].x; ct[1] += w_c[w].y; ct[2] += w_c[w].z; ct[3] += w_c[w].w;
        }
        float L = 0.f, V = 0.f;
#pragma unroll
        for (int q = 0; q < 4; ++q) {
            const float np = (float)(ct[q] & 0xFFFFu);
            const float nn = (float)(ct[q] >> 16);
            const bool valid = (np > 0.f) && (nn > 0.f);
            const float l = sp[q] / fmaxf(np, 1.f) + sn[q] / fmaxf(nn, 1.f);
            L += valid ? l   : 0.f;
            V += valid ? 1.f : 0.f;
        }
        atomicAdd(&LV[0], L);
        atomicAdd(&LV[1], V);
    }
}

// ---------------------------------------------------------------------------
__global__ void nrl_final_kernel(const float* __restrict__ LV,
                                 float* __restrict__ out)
{
    out[0] = LV[0] / fmaxf(LV[1], 1.0f);
}

// ---------------------------------------------------------------------------
extern "C" void kernel_launch(void* const* d_in, const int* in_sizes, int n_in,
                              void* d_out, int out_size, void* d_ws, size_t ws_size,
                              hipStream_t stream)
{
    const float* pred   = (const float*)d_in[0];
    const int*   labels = (const int*)d_in[1];
    const int N = in_sizes[0] / C_DIM;

    const size_t bytes512 = 3ull * 512 * CPAD * 4ull + 16;   // 6.30 MB
    const size_t bytes256 = 3ull * 256 * CPAD * 4ull + 16;   // 3.15 MB

    int store_mode, S, nblk;
    if (ws_size >= bytes512) {
        store_mode = 1; S = 512; nblk = 512;   // 2 blocks/CU -> 32 waves/CU
    } else if (ws_size >= bytes256) {
        store_mode = 1; S = 256; nblk = 256;
    } else {
        store_mode = 0; nblk = 256;
        S = (int)((ws_size - 16) / (3ull * CPAD * 4ull));
        if (S > 64) S = 64;
        if (S < 1)  S = 1;
    }

    float*        ws_sp_pos = (float*)d_ws;
    float*        ws_sp_neg = ws_sp_pos + (size_t)S * CPAD;
    unsigned int* ws_cnt    = (unsigned int*)(ws_sp_neg + (size_t)S * CPAD);
    float*        LV        = (float*)(ws_cnt + (size_t)S * CPAD);

    if (store_mode) {
        hipMemsetAsync(LV, 0, 2 * sizeof(float), stream);
    } else {
        hipMemsetAsync(d_ws, 0, 3ull * S * CPAD * 4ull + 2 * sizeof(float), stream);
    }

    nrl_partial_kernel<<<nblk, 1024, 0, stream>>>(pred, labels,
                                                  ws_sp_pos, ws_sp_neg, ws_cnt,
                                                  N, S, store_mode);
    nrl_reduce_kernel<<<250, 256, 0, stream>>>(ws_sp_pos, ws_sp_neg,
                                               ws_cnt, LV, S);
    nrl_final_kernel<<<1, 1, 0, stream>>>(LV, (float*)d_out);
}

// Round 7
// 55.877 us; speedup vs baseline: 1.1730x; 1.1727x over previous
//
#include <hip/hip_runtime.h>

#define C_DIM 1000
#define WPC   3             // words per column: sp, sn, cnt interleaved
#define RSTR  3072          // row stride in words (3000 used, padded)

typedef float f32x4 __attribute__((ext_vector_type(4)));
typedef int   i32x4 __attribute__((ext_vector_type(4)));

// Inline-asm 16B loads (R6): ordered volatile asm keeps all 8 loads in flight.
#define GLOAD(dst, addr) \
    asm volatile("global_load_dwordx4 %0, %1, off" : "=v"(dst) : "v"(addr))

// ---------------------------------------------------------------------------
// Kernel 1: streaming partial reduction (proven ~5 TB/s touch in timed runs).
// 1024 threads = 4 row-groups x 256 (250 active). Group g of block b streams
// rows v = b*4+g step 4*grid. Groups merge via LDS; block writes a 3000-word
// partial [col-major interleaved sp,sn,cnt] to slice blockIdx, fully coalesced.
// Block 0 thread 0 zeroes the kernel2 ticket (device atomic, proven coherent).
//
// softplus(x)  = max(x,0)  + ln2 * log2(1 + 2^(-|x|*log2e))   (log2 term shared)
// Labels are {0,1}; counts pack as (n_pos | n_neg<<16).
// ---------------------------------------------------------------------------
__global__ __launch_bounds__(1024) void nrl_partial_kernel(
    const float* __restrict__ pred,
    const int*   __restrict__ labels,
    unsigned int* __restrict__ ws_data,   // [S][RSTR] words
    unsigned int* __restrict__ ticket,
    int N, int S, int store_mode)
{
    const int g   = threadIdx.x >> 8;     // row-group 0..3
    const int tid = threadIdx.x & 255;    // lane-in-group

    if (blockIdx.x == 0 && threadIdx.x == 0) atomicExch(ticket, 0u);

    __shared__ float        s_sp[4][1024];
    __shared__ float        s_sn[4][1024];
    __shared__ unsigned int s_ct[4][1024];

    const float NEG_LOG2E = -1.4426950408889634f;
    const float LN2       =  0.6931471805599453f;

    float l2p[4] = {0.f,0.f,0.f,0.f};
    float l2n[4] = {0.f,0.f,0.f,0.f};
    float lip[4] = {0.f,0.f,0.f,0.f};
    float lin[4] = {0.f,0.f,0.f,0.f};
    unsigned int cnt[4] = {0u,0u,0u,0u};

#define PROC(P, Y)                                                          \
    {                                                                       \
        _Pragma("unroll")                                                   \
        for (int j = 0; j < 4; ++j) {                                       \
            const float x  = (P)[j];                                        \
            const float u  = NEG_LOG2E * fabsf(x);                          \
            const float e2 = __builtin_amdgcn_exp2f(u);                     \
            const float l2 = __builtin_amdgcn_logf(1.0f + e2);              \
            const float r  = fmaxf(x, 0.0f);                                \
            const float rn = r - x; /* = max(-x,0) */                       \
            const bool isp = ((Y)[j] == 1);                                 \
            l2p[j] += isp ? l2 : 0.0f;                                      \
            l2n[j] += isp ? 0.0f : l2;                                      \
            lip[j] += isp ? rn : 0.0f;                                      \
            lin[j] += isp ? 0.0f : r;                                       \
            cnt[j] += isp ? 1u : 0x10000u;                                  \
        }                                                                   \
    }

    if (tid < 250) {
        const int c0 = tid * 4;
        const int v       = (blockIdx.x << 2) | g;
        const int vstride = gridDim.x << 2;

        int r = v;
        for (; r + 3 * vstride < N; r += 4 * vstride) {
            const size_t b0 = (size_t)r * C_DIM + c0;
            const size_t b1 = (size_t)(r +     vstride) * C_DIM + c0;
            const size_t b2 = (size_t)(r + 2 * vstride) * C_DIM + c0;
            const size_t b3 = (size_t)(r + 3 * vstride) * C_DIM + c0;

            f32x4 p0, p1, p2, p3;
            i32x4 y0, y1, y2, y3;
            GLOAD(p0, pred + b0);   GLOAD(y0, labels + b0);
            GLOAD(p1, pred + b1);   GLOAD(y1, labels + b1);
            GLOAD(p2, pred + b2);   GLOAD(y2, labels + b2);
            GLOAD(p3, pred + b3);   GLOAD(y3, labels + b3);
            asm volatile("s_waitcnt vmcnt(0)" ::: "memory");
            __builtin_amdgcn_sched_barrier(0);
            PROC(p0, y0) PROC(p1, y1) PROC(p2, y2) PROC(p3, y3)
        }
        for (; r < N; r += vstride) {
            const size_t b0 = (size_t)r * C_DIM + c0;
            const f32x4 p0 = *reinterpret_cast<const f32x4*>(pred + b0);
            const i32x4 y0 = *reinterpret_cast<const i32x4*>(labels + b0);
            PROC(p0, y0)
        }
#undef PROC

        float4 vp, vn; uint4 vc;
        vp.x = l2p[0]*LN2 + lip[0]; vp.y = l2p[1]*LN2 + lip[1];
        vp.z = l2p[2]*LN2 + lip[2]; vp.w = l2p[3]*LN2 + lip[3];
        vn.x = l2n[0]*LN2 + lin[0]; vn.y = l2n[1]*LN2 + lin[1];
        vn.z = l2n[2]*LN2 + lin[2]; vn.w = l2n[3]*LN2 + lin[3];
        vc.x = cnt[0]; vc.y = cnt[1]; vc.z = cnt[2]; vc.w = cnt[3];
        *reinterpret_cast<float4*>(&s_sp[g][c0]) = vp;
        *reinterpret_cast<float4*>(&s_sn[g][c0]) = vn;
        *reinterpret_cast<uint4*>(&s_ct[g][c0])  = vc;
    }
    __syncthreads();

    // merge 4 groups; result into registers (all threads t<1000)
    const int t = threadIdx.x;
    float sp = 0.f, sn = 0.f;
    unsigned int c = 0u;
    if (t < C_DIM) {
        sp = s_sp[0][t] + s_sp[1][t] + s_sp[2][t] + s_sp[3][t];
        sn = s_sn[0][t] + s_sn[1][t] + s_sn[2][t] + s_sn[3][t];
        c  = s_ct[0][t] + s_ct[1][t] + s_ct[2][t] + s_ct[3][t];
    }
    __syncthreads();   // all reads of s_* done before staging overwrites

    // stage interleaved [3t]=sp [3t+1]=sn [3t+2]=cnt (stride-3: bank-conflict-free)
    unsigned int* stage = reinterpret_cast<unsigned int*>(&s_sp[0][0]); // 4096 words avail
    if (t < C_DIM) {
        stage[3*t + 0] = __float_as_uint(sp);
        stage[3*t + 1] = __float_as_uint(sn);
        stage[3*t + 2] = c;
    }
    __syncthreads();

    if (store_mode) {
        unsigned int* dst = ws_data + (size_t)blockIdx.x * RSTR;
        for (int w = threadIdx.x; w < WPC * C_DIM; w += 1024)   // coalesced
            dst[w] = stage[w];
    } else {
        unsigned int* dst = ws_data + (size_t)(blockIdx.x % S) * RSTR;
        for (int w = threadIdx.x; w < WPC * C_DIM; w += 1024) {
            if ((w % 3) == 2) atomicAdd(&dst[w], stage[w]);
            else              atomicAdd((float*)&dst[w], __uint_as_float(stage[w]));
        }
    }
}

// ---------------------------------------------------------------------------
// Kernel 2: block j reduces column-quad j across S slices (1 cache line per
// slice-quad thanks to interleaving), writes its (L,V) partial via atomicExch,
// takes a ticket; the last block reduces the 250 partials and writes out[0].
// ---------------------------------------------------------------------------
__global__ __launch_bounds__(256) void nrl_reduce_kernel(
    const unsigned int* __restrict__ ws_data,
    float*        __restrict__ pb,      // [250][2] partial L,V
    unsigned int* __restrict__ ticket,
    float* __restrict__ out, int S)
{
    const int j = blockIdx.x;           // column quad 0..249
    float sp[4] = {0.f,0.f,0.f,0.f};
    float sn[4] = {0.f,0.f,0.f,0.f};
    unsigned int ct[4] = {0u,0u,0u,0u};

    for (int s = threadIdx.x; s < S; s += 256) {
        const unsigned int* row = ws_data + (size_t)s * RSTR + j * 12;
        const uint4 A = *reinterpret_cast<const uint4*>(row + 0);
        const uint4 B = *reinterpret_cast<const uint4*>(row + 4);
        const uint4 C = *reinterpret_cast<const uint4*>(row + 8);
        sp[0] += __uint_as_float(A.x); sn[0] += __uint_as_float(A.y); ct[0] += A.z;
        sp[1] += __uint_as_float(A.w); sn[1] += __uint_as_float(B.x); ct[1] += B.y;
        sp[2] += __uint_as_float(B.z); sn[2] += __uint_as_float(B.w); ct[2] += C.x;
        sp[3] += __uint_as_float(C.y); sn[3] += __uint_as_float(C.z); ct[3] += C.w;
    }

#pragma unroll
    for (int off = 32; off > 0; off >>= 1) {
#pragma unroll
        for (int q = 0; q < 4; ++q) {
            sp[q] += __shfl_down(sp[q], off);
            sn[q] += __shfl_down(sn[q], off);
            ct[q] += __shfl_down(ct[q], off);
        }
    }

    __shared__ float        w_sp[4][4], w_sn[4][4];
    __shared__ unsigned int w_ct[4][4];
    const int wid  = threadIdx.x >> 6;
    const int lane = threadIdx.x & 63;
    if (lane == 0) {
#pragma unroll
        for (int q = 0; q < 4; ++q) { w_sp[wid][q]=sp[q]; w_sn[wid][q]=sn[q]; w_ct[wid][q]=ct[q]; }
    }
    __syncthreads();

    __shared__ int s_last;
    if (threadIdx.x == 0) {
        float L = 0.f, V = 0.f;
#pragma unroll
        for (int q = 0; q < 4; ++q) {
            float tsp = 0.f, tsn = 0.f; unsigned int tct = 0u;
#pragma unroll
            for (int w = 0; w < 4; ++w) { tsp+=w_sp[w][q]; tsn+=w_sn[w][q]; tct+=w_ct[w][q]; }
            const float np = (float)(tct & 0xFFFFu);
            const float nn = (float)(tct >> 16);
            const bool valid = (np > 0.f) && (nn > 0.f);
            const float l = tsp / fmaxf(np, 1.f) + tsn / fmaxf(nn, 1.f);
            L += valid ? l   : 0.f;
            V += valid ? 1.f : 0.f;
        }
        atomicExch(&pb[2*j + 0], L);
        atomicExch(&pb[2*j + 1], V);
        __threadfence();
        const unsigned int old = atomicAdd(ticket, 1u);
        s_last = (old == (unsigned int)(gridDim.x - 1)) ? 1 : 0;
    }
    __syncthreads();

    if (s_last) {
        const int t = threadIdx.x;
        float l = 0.f, v = 0.f;
        if (t < 250) {
            l = atomicAdd(&pb[2*t + 0], 0.0f);   // coherent device-scope read
            v = atomicAdd(&pb[2*t + 1], 0.0f);
        }
#pragma unroll
        for (int off = 32; off > 0; off >>= 1) {
            l += __shfl_down(l, off);
            v += __shfl_down(v, off);
        }
        __shared__ float f_l[4], f_v[4];
        if (lane == 0) { f_l[wid] = l; f_v[wid] = v; }
        __syncthreads();
        if (t == 0) {
            const float L = f_l[0] + f_l[1] + f_l[2] + f_l[3];
            const float V = f_v[0] + f_v[1] + f_v[2] + f_v[3];
            out[0] = L / fmaxf(V, 1.0f);
        }
    }
}

// ---------------------------------------------------------------------------
extern "C" void kernel_launch(void* const* d_in, const int* in_sizes, int n_in,
                              void* d_out, int out_size, void* d_ws, size_t ws_size,
                              hipStream_t stream)
{
    const float* pred   = (const float*)d_in[0];
    const int*   labels = (const int*)d_in[1];
    const int N = in_sizes[0] / C_DIM;

    const size_t tail      = 500 * 4 + 64;                     // pb + ticket
    const size_t bytes512  = (size_t)512 * RSTR * 4 + tail;    // ~6.30 MB
    const size_t bytes256  = (size_t)256 * RSTR * 4 + tail;    // ~3.15 MB

    int store_mode, S, nblk;
    if (ws_size >= bytes512) {
        store_mode = 1; S = 512; nblk = 512;   // 2 blocks/CU -> 32 waves/CU
    } else if (ws_size >= bytes256) {
        store_mode = 1; S = 256; nblk = 256;
    } else {
        store_mode = 0; nblk = 256;
        S = (int)((ws_size - tail) / ((size_t)RSTR * 4));
        if (S > 64) S = 64;
        if (S < 1)  S = 1;
    }

    unsigned int* ws_data = (unsigned int*)d_ws;
    float*        pb      = (float*)(ws_data + (size_t)S * RSTR);
    unsigned int* ticket  = (unsigned int*)(pb + 500);

    if (!store_mode) {
        hipMemsetAsync(ws_data, 0, (size_t)S * RSTR * 4, stream);
    }

    nrl_partial_kernel<<<nblk, 1024, 0, stream>>>(pred, labels, ws_data, ticket,
                                                  N, S, store_mode);
    nrl_reduce_kernel<<<250, 256, 0, stream>>>(ws_data, pb, ticket,
                                               (float*)d_out, S);
}

// Round 8
// 54.823 us; speedup vs baseline: 1.1956x; 1.0192x over previous
//
#include <hip/hip_runtime.h>

#define C_DIM 1000
#define WPC   3             // words per column: sp, sn, cnt interleaved
#define RSTR  3072          // row stride in words (3000 used, padded)

typedef float f32x4 __attribute__((ext_vector_type(4)));
typedef int   i32x4 __attribute__((ext_vector_type(4)));

// Inline-asm 16B loads (R6): ordered volatile asm keeps all 8 loads in flight.
#define GLOAD(dst, addr) \
    asm volatile("global_load_dwordx4 %0, %1, off" : "=v"(dst) : "v"(addr))

// ---------------------------------------------------------------------------
// Kernel 1: streaming partial reduction.
// R8 change: CONTIGUOUS stream partition. Stream s = blockIdx*4 + g owns rows
// [s*q .. s*q+q) contiguously (q = N/2048 = 16), read as 4-consecutive-row
// chunks -> each group's 8 in-flight loads cover one contiguous 16 KB window,
// advancing sequentially (DRAM row-buffer friendly). Previous round-robin
// pattern put consecutive loads 8.2 MB apart -> ~40% HBM efficiency.
//
// softplus(x)  = max(x,0)  + ln2 * log2(1 + 2^(-|x|*log2e))   (log2 term shared)
// Labels are {0,1}; counts pack as (n_pos | n_neg<<16).
// ---------------------------------------------------------------------------
__global__ __launch_bounds__(1024) void nrl_partial_kernel(
    const float* __restrict__ pred,
    const int*   __restrict__ labels,
    unsigned int* __restrict__ ws_data,   // [S][RSTR] words
    unsigned int* __restrict__ ticket,
    int N, int S, int store_mode)
{
    const int g   = threadIdx.x >> 8;     // row-group 0..3
    const int tid = threadIdx.x & 255;    // lane-in-group

    if (blockIdx.x == 0 && threadIdx.x == 0) atomicExch(ticket, 0u);

    __shared__ float        s_sp[4][1024];
    __shared__ float        s_sn[4][1024];
    __shared__ unsigned int s_ct[4][1024];

    const float NEG_LOG2E = -1.4426950408889634f;
    const float LN2       =  0.6931471805599453f;

    float l2p[4] = {0.f,0.f,0.f,0.f};
    float l2n[4] = {0.f,0.f,0.f,0.f};
    float lip[4] = {0.f,0.f,0.f,0.f};
    float lin[4] = {0.f,0.f,0.f,0.f};
    unsigned int cnt[4] = {0u,0u,0u,0u};

#define PROC(P, Y)                                                          \
    {                                                                       \
        _Pragma("unroll")                                                   \
        for (int j = 0; j < 4; ++j) {                                       \
            const float x  = (P)[j];                                        \
            const float u  = NEG_LOG2E * fabsf(x);                          \
            const float e2 = __builtin_amdgcn_exp2f(u);                     \
            const float l2 = __builtin_amdgcn_logf(1.0f + e2);              \
            const float r  = fmaxf(x, 0.0f);                                \
            const float rn = r - x; /* = max(-x,0) */                       \
            const bool isp = ((Y)[j] == 1);                                 \
            l2p[j] += isp ? l2 : 0.0f;                                      \
            l2n[j] += isp ? 0.0f : l2;                                      \
            lip[j] += isp ? rn : 0.0f;                                      \
            lin[j] += isp ? 0.0f : r;                                       \
            cnt[j] += isp ? 1u : 0x10000u;                                  \
        }                                                                   \
    }

    if (tid < 250) {
        const int c0 = tid * 4;

        // balanced contiguous partition of N rows over (gridDim*4) streams
        const int nstreams = gridDim.x << 2;
        const int sid = (blockIdx.x << 2) | g;
        const int q   = N / nstreams;
        const int rem = N % nstreams;
        const int r0  = sid * q + (sid < rem ? sid : rem);
        const int r1  = r0 + q + (sid < rem ? 1 : 0);

        int r = r0;
        for (; r + 4 <= r1; r += 4) {
            const size_t b0 = (size_t)r * C_DIM + c0;           // rows r..r+3
            const size_t b1 = b0 + C_DIM;
            const size_t b2 = b0 + 2 * C_DIM;
            const size_t b3 = b0 + 3 * C_DIM;

            f32x4 p0, p1, p2, p3;
            i32x4 y0, y1, y2, y3;
            GLOAD(p0, pred + b0);   GLOAD(y0, labels + b0);
            GLOAD(p1, pred + b1);   GLOAD(y1, labels + b1);
            GLOAD(p2, pred + b2);   GLOAD(y2, labels + b2);
            GLOAD(p3, pred + b3);   GLOAD(y3, labels + b3);
            asm volatile("s_waitcnt vmcnt(0)" ::: "memory");
            __builtin_amdgcn_sched_barrier(0);
            PROC(p0, y0) PROC(p1, y1) PROC(p2, y2) PROC(p3, y3)
        }
        for (; r < r1; ++r) {
            const size_t b0 = (size_t)r * C_DIM + c0;
            const f32x4 p0 = *reinterpret_cast<const f32x4*>(pred + b0);
            const i32x4 y0 = *reinterpret_cast<const i32x4*>(labels + b0);
            PROC(p0, y0)
        }
#undef PROC

        float4 vp, vn; uint4 vc;
        vp.x = l2p[0]*LN2 + lip[0]; vp.y = l2p[1]*LN2 + lip[1];
        vp.z = l2p[2]*LN2 + lip[2]; vp.w = l2p[3]*LN2 + lip[3];
        vn.x = l2n[0]*LN2 + lin[0]; vn.y = l2n[1]*LN2 + lin[1];
        vn.z = l2n[2]*LN2 + lin[2]; vn.w = l2n[3]*LN2 + lin[3];
        vc.x = cnt[0]; vc.y = cnt[1]; vc.z = cnt[2]; vc.w = cnt[3];
        *reinterpret_cast<float4*>(&s_sp[g][c0]) = vp;
        *reinterpret_cast<float4*>(&s_sn[g][c0]) = vn;
        *reinterpret_cast<uint4*>(&s_ct[g][c0])  = vc;
    }
    __syncthreads();

    // merge 4 groups; result into registers
    const int t = threadIdx.x;
    float sp = 0.f, sn = 0.f;
    unsigned int c = 0u;
    if (t < C_DIM) {
        sp = s_sp[0][t] + s_sp[1][t] + s_sp[2][t] + s_sp[3][t];
        sn = s_sn[0][t] + s_sn[1][t] + s_sn[2][t] + s_sn[3][t];
        c  = s_ct[0][t] + s_ct[1][t] + s_ct[2][t] + s_ct[3][t];
    }
    __syncthreads();   // all reads of s_* done before staging overwrites

    // stage interleaved [3t]=sp [3t+1]=sn [3t+2]=cnt (stride-3: conflict-free)
    unsigned int* stage = reinterpret_cast<unsigned int*>(&s_sp[0][0]);
    if (t < C_DIM) {
        stage[3*t + 0] = __float_as_uint(sp);
        stage[3*t + 1] = __float_as_uint(sn);
        stage[3*t + 2] = c;
    }
    __syncthreads();

    if (store_mode) {
        unsigned int* dst = ws_data + (size_t)blockIdx.x * RSTR;
        for (int w = threadIdx.x; w < WPC * C_DIM; w += 1024)   // coalesced
            dst[w] = stage[w];
    } else {
        unsigned int* dst = ws_data + (size_t)(blockIdx.x % S) * RSTR;
        for (int w = threadIdx.x; w < WPC * C_DIM; w += 1024) {
            if ((w % 3) == 2) atomicAdd(&dst[w], stage[w]);
            else              atomicAdd((float*)&dst[w], __uint_as_float(stage[w]));
        }
    }
}

// ---------------------------------------------------------------------------
// Kernel 2: block j reduces column-quad j across S slices, writes its (L,V)
// partial, takes a ticket; last block reduces the 250 partials into out[0].
// ---------------------------------------------------------------------------
__global__ __launch_bounds__(256) void nrl_reduce_kernel(
    const unsigned int* __restrict__ ws_data,
    float*        __restrict__ pb,      // [250][2] partial L,V
    unsigned int* __restrict__ ticket,
    float* __restrict__ out, int S)
{
    const int j = blockIdx.x;           // column quad 0..249
    float sp[4] = {0.f,0.f,0.f,0.f};
    float sn[4] = {0.f,0.f,0.f,0.f};
    unsigned int ct[4] = {0u,0u,0u,0u};

    for (int s = threadIdx.x; s < S; s += 256) {
        const unsigned int* row = ws_data + (size_t)s * RSTR + j * 12;
        const uint4 A = *reinterpret_cast<const uint4*>(row + 0);
        const uint4 B = *reinterpret_cast<const uint4*>(row + 4);
        const uint4 C = *reinterpret_cast<const uint4*>(row + 8);
        sp[0] += __uint_as_float(A.x); sn[0] += __uint_as_float(A.y); ct[0] += A.z;
        sp[1] += __uint_as_float(A.w); sn[1] += __uint_as_float(B.x); ct[1] += B.y;
        sp[2] += __uint_as_float(B.z); sn[2] += __uint_as_float(B.w); ct[2] += C.x;
        sp[3] += __uint_as_float(C.y); sn[3] += __uint_as_float(C.z); ct[3] += C.w;
    }

#pragma unroll
    for (int off = 32; off > 0; off >>= 1) {
#pragma unroll
        for (int q = 0; q < 4; ++q) {
            sp[q] += __shfl_down(sp[q], off);
            sn[q] += __shfl_down(sn[q], off);
            ct[q] += __shfl_down(ct[q], off);
        }
    }

    __shared__ float        w_sp[4][4], w_sn[4][4];
    __shared__ unsigned int w_ct[4][4];
    const int wid  = threadIdx.x >> 6;
    const int lane = threadIdx.x & 63;
    if (lane == 0) {
#pragma unroll
        for (int q = 0; q < 4; ++q) { w_sp[wid][q]=sp[q]; w_sn[wid][q]=sn[q]; w_ct[wid][q]=ct[q]; }
    }
    __syncthreads();

    __shared__ int s_last;
    if (threadIdx.x == 0) {
        float L = 0.f, V = 0.f;
#pragma unroll
        for (int q = 0; q < 4; ++q) {
            float tsp = 0.f, tsn = 0.f; unsigned int tct = 0u;
#pragma unroll
            for (int w = 0; w < 4; ++w) { tsp+=w_sp[w][q]; tsn+=w_sn[w][q]; tct+=w_ct[w][q]; }
            const float np = (float)(tct & 0xFFFFu);
            const float nn = (float)(tct >> 16);
            const bool valid = (np > 0.f) && (nn > 0.f);
            const float l = tsp / fmaxf(np, 1.f) + tsn / fmaxf(nn, 1.f);
            L += valid ? l   : 0.f;
            V += valid ? 1.f : 0.f;
        }
        atomicExch(&pb[2*j + 0], L);
        atomicExch(&pb[2*j + 1], V);
        __threadfence();
        const unsigned int old = atomicAdd(ticket, 1u);
        s_last = (old == (unsigned int)(gridDim.x - 1)) ? 1 : 0;
    }
    __syncthreads();

    if (s_last) {
        const int t = threadIdx.x;
        float l = 0.f, v = 0.f;
        if (t < 250) {
            l = atomicAdd(&pb[2*t + 0], 0.0f);   // coherent device-scope read
            v = atomicAdd(&pb[2*t + 1], 0.0f);
        }
#pragma unroll
        for (int off = 32; off > 0; off >>= 1) {
            l += __shfl_down(l, off);
            v += __shfl_down(v, off);
        }
        __shared__ float f_l[4], f_v[4];
        if (lane == 0) { f_l[wid] = l; f_v[wid] = v; }
        __syncthreads();
        if (t == 0) {
            const float L = f_l[0] + f_l[1] + f_l[2] + f_l[3];
            const float V = f_v[0] + f_v[1] + f_v[2] + f_v[3];
            out[0] = L / fmaxf(V, 1.0f);
        }
    }
}

// ---------------------------------------------------------------------------
extern "C" void kernel_launch(void* const* d_in, const int* in_sizes, int n_in,
                              void* d_out, int out_size, void* d_ws, size_t ws_size,
                              hipStream_t stream)
{
    const float* pred   = (const float*)d_in[0];
    const int*   labels = (const int*)d_in[1];
    const int N = in_sizes[0] / C_DIM;

    const size_t tail      = 500 * 4 + 64;                     // pb + ticket
    const size_t bytes512  = (size_t)512 * RSTR * 4 + tail;    // ~6.30 MB
    const size_t bytes256  = (size_t)256 * RSTR * 4 + tail;    // ~3.15 MB

    int store_mode, S, nblk;
    if (ws_size >= bytes512) {
        store_mode = 1; S = 512; nblk = 512;   // 2 blocks/CU
    } else if (ws_size >= bytes256) {
        store_mode = 1; S = 256; nblk = 256;
    } else {
        store_mode = 0; nblk = 256;
        S = (int)((ws_size - tail) / ((size_t)RSTR * 4));
        if (S > 64) S = 64;
        if (S < 1)  S = 1;
    }

    unsigned int* ws_data = (unsigned int*)d_ws;
    float*        pb      = (float*)(ws_data + (size_t)S * RSTR);
    unsigned int* ticket  = (unsigned int*)(pb + 500);

    if (!store_mode) {
        hipMemsetAsync(ws_data, 0, (size_t)S * RSTR * 4, stream);
    }

    nrl_partial_kernel<<<nblk, 1024, 0, stream>>>(pred, labels, ws_data, ticket,
                                                  N, S, store_mode);
    nrl_reduce_kernel<<<250, 256, 0, stream>>>(ws_data, pb, ticket,
                                               (float*)d_out, S);
}